// Round 2
// baseline (739.208 us; speedup 1.0000x reference)
//
#include <hip/hip_runtime.h>

typedef unsigned int uint;
typedef unsigned short ushort_t;
typedef __bf16 bf16x8 __attribute__((ext_vector_type(8)));
typedef float f32x4 __attribute__((ext_vector_type(4)));

__device__ __forceinline__ int imin(int a, int b){ return a<b?a:b; }
__device__ __forceinline__ int imax(int a, int b){ return a>b?a:b; }

__device__ __forceinline__ ushort_t f2b(float f){
  uint u = __builtin_bit_cast(uint, f);
  u += 0x7FFFu + ((u>>16)&1u);          // round-to-nearest-even
  return (ushort_t)(u>>16);
}
__device__ __forceinline__ float b2f(ushort_t s){
  uint u = ((uint)s)<<16;
  return __builtin_bit_cast(float, u);
}
__device__ __forceinline__ f32x4 fz4(){ f32x4 z; z[0]=0.f; z[1]=0.f; z[2]=0.f; z[3]=0.f; return z; }

// ---------------- fp32 -> bf16 pre-convert ----------------
// Converts activations + weights ONCE (instead of per-GEMM-block). Scratch
// lives in the attn_out region (dead until attn_k overwrites it).
struct CJob { const float* src; ushort_t* dst; int nvec; };  // nvec = elems/8

__global__ __launch_bounds__(256) void convert_k(CJob j0, CJob j1, CJob j2,
                                                 CJob j3, CJob j4, CJob j5)
{
  CJob jb;
  switch (blockIdx.y){
    case 0: jb=j0; break; case 1: jb=j1; break; case 2: jb=j2; break;
    case 3: jb=j3; break; case 4: jb=j4; break; default: jb=j5; break;
  }
  int stride = gridDim.x*256;
  for (int i = blockIdx.x*256 + threadIdx.x; i < jb.nvec; i += stride){
    const float4* s = (const float4*)(jb.src + (size_t)i*8);
    float4 v0 = s[0], v1 = s[1];
    uint4 pk;
    pk.x = (uint)f2b(v0.x) | ((uint)f2b(v0.y)<<16);
    pk.y = (uint)f2b(v0.z) | ((uint)f2b(v0.w)<<16);
    pk.z = (uint)f2b(v1.x) | ((uint)f2b(v1.y)<<16);
    pk.w = (uint)f2b(v1.z) | ((uint)f2b(v1.w)<<16);
    *(uint4*)(jb.dst + (size_t)i*8) = pk;
  }
}

// ---------------- GEMM: C[M,N] = A[M,K] @ W[N,K]^T + bias ----------------
// M=4096, N=1024, K=1024. 128x128 tile, BK=32, 256 threads (4 waves, 64x64).
// A and W are pre-converted bf16 -> staging is pure uint4 loads (no VALU f2b,
// half the fetch bytes of the fp32 path).
struct GArg { const ushort_t* A; const ushort_t* W; const float* bias; void* O; };

template<bool OBF16>
__global__ __launch_bounds__(256) void gemm_nt(GArg g0, GArg g1, GArg g2)
{
  GArg g = (blockIdx.z==0) ? g0 : ((blockIdx.z==1) ? g1 : g2);
  // LDS rows padded to 40 elems (80 B): 20-dword stride -> uniform bank spread
  __shared__ ushort_t As[128*40];
  __shared__ ushort_t Bs[128*40];
  const int tid  = threadIdx.x;
  const int lane = tid & 63;
  const int w    = tid >> 6;
  const int ml   = lane & 15, quad = lane >> 4;
  const int m0 = blockIdx.y*128, n0 = blockIdx.x*128;
  const int wm = (w>>1)*64, wn = (w&1)*64;

  f32x4 acc[4][4];
  #pragma unroll
  for (int i=0;i<4;i++)
    #pragma unroll
    for (int j=0;j<4;j++) acc[i][j]=fz4();

  for (int kt=0; kt<32; ++kt){
    // ---- stage A and B tiles (128 x 32 bf16 each) ----
    #pragma unroll
    for (int i=0;i<2;i++){
      int s   = tid + i*256;          // 512 slots of 8 elems
      int row = s>>2, c = s&3;
      int kof = kt*32 + c*8;
      *(uint4*)&As[row*40 + c*8] = *(const uint4*)(g.A + (size_t)(m0+row)*1024 + kof);
      *(uint4*)&Bs[row*40 + c*8] = *(const uint4*)(g.W + (size_t)(n0+row)*1024 + kof);
    }
    __syncthreads();
    // ---- fragments + 16 MFMAs ----
    bf16x8 af[4], bfr[4];
    #pragma unroll
    for (int t4=0;t4<4;t4++)
      af[t4]  = __builtin_bit_cast(bf16x8, *(const uint4*)&As[(wm + t4*16 + ml)*40 + quad*8]);
    #pragma unroll
    for (int t4=0;t4<4;t4++)
      bfr[t4] = __builtin_bit_cast(bf16x8, *(const uint4*)&Bs[(wn + t4*16 + ml)*40 + quad*8]);
    #pragma unroll
    for (int ti=0;ti<4;ti++)
      #pragma unroll
      for (int tj=0;tj<4;tj++)
        acc[ti][tj] = __builtin_amdgcn_mfma_f32_16x16x32_bf16(af[ti], bfr[tj], acc[ti][tj], 0,0,0);
    __syncthreads();
  }
  // ---- epilogue: C row=(lane>>4)*4+reg, col=lane&15 (m89-verified layout) ----
  #pragma unroll
  for (int tj=0;tj<4;tj++){
    int gcol = n0 + wn + tj*16 + ml;
    float bv = g.bias[gcol];
    #pragma unroll
    for (int ti=0;ti<4;ti++){
      int growb = m0 + wm + ti*16 + quad*4;
      #pragma unroll
      for (int r=0;r<4;r++){
        float val = acc[ti][tj][r] + bv;
        size_t off = (size_t)(growb + r)*1024 + gcol;
        if (OBF16) ((ushort_t*)g.O)[off] = f2b(val);
        else       ((float*)g.O)[off]    = val;
      }
    }
  }
}

// ---------------- sparse attention ----------------
// wg = (b, h, 32 query rows). 128 threads = 2 waves; wave w owns rows 16w..16w+15.
// Slots: 0..255 strided (j=8*slot), 256..351 local (j = i0-32 + slot-256).
// stash is bf16: halves LDS (23.2 KB -> ~7 blocks/CU instead of 3) and
// lets phase 3 feed P straight into MFMA A-fragments.
#define SW2 360   // row stride in bf16 elems; 720 B = 180 dw -> decent bank spread
__global__ __launch_bounds__(128) void attn_k(
    const ushort_t* Qb, const ushort_t* Kb, const ushort_t* Vb,
    ushort_t* Ctxb, float* attn_out)
{
  __shared__ ushort_t stash[32*SW2];   // unnormalized exp(score), bf16
  __shared__ float invl[32];           // 1 / row-sum
  const int lane = threadIdx.x & 63;
  const int w    = threadIdx.x >> 6;
  const int ml   = lane & 15, quad = lane >> 4;
  const int tile = blockIdx.x, h = blockIdx.y, b = blockIdx.z;
  const int i0  = tile*32;
  const int jl0 = i0 - 32;
  const int rb  = 16*w;
  const size_t bh = (size_t)b*2048*1024 + (size_t)h*64;

  // ---- phase 1: scores -> exp -> stash; row-sums ----
  bf16x8 aq0, aq1;
  {
    const ushort_t* qp = Qb + bh + (size_t)(i0 + rb + ml)*1024 + quad*8;
    aq0 = __builtin_bit_cast(bf16x8, *(const uint4*)qp);
    aq1 = __builtin_bit_cast(bf16x8, *(const uint4*)(qp + 32));
  }
  float lsum[4] = {0.f,0.f,0.f,0.f};
  for (int c=0;c<22;c++){
    int j  = (c<16) ? (128*c + 8*ml) : (jl0 + 16*(c-16) + ml);
    int jc = imin(imax(j,0),2047);
    const ushort_t* kp = Kb + bh + (size_t)jc*1024 + quad*8;
    bf16x8 kb0 = __builtin_bit_cast(bf16x8, *(const uint4*)kp);
    bf16x8 kb1 = __builtin_bit_cast(bf16x8, *(const uint4*)(kp + 32));
    f32x4 sc = fz4();
    sc = __builtin_amdgcn_mfma_f32_16x16x32_bf16(aq0, kb0, sc, 0,0,0);
    sc = __builtin_amdgcn_mfma_f32_16x16x32_bf16(aq1, kb1, sc, 0,0,0);
    int slot = 16*c + ml;
    #pragma unroll
    for (int r=0;r<4;r++){
      int rl = rb + quad*4 + r;
      int i  = i0 + rl;
      bool valid = (c<16) ? true :
        ((j>=0) && (j<2048) && ((j&7)!=0) && (j >= i-32) && (j < i+32));
      float e = valid ? __expf(sc[r]*0.125f) : 0.f;   // masked -> exact 0
      ushort_t eb = f2b(e);
      lsum[r] += b2f(eb);                 // sum the ROUNDED values: rows sum to 1
      stash[rl*SW2 + slot] = eb;
    }
  }
  #pragma unroll
  for (int off=1; off<16; off<<=1){
    #pragma unroll
    for (int r=0;r<4;r++) lsum[r] += __shfl_xor(lsum[r], off);
  }
  if (ml==0){
    #pragma unroll
    for (int r=0;r<4;r++) invl[rb + quad*4 + r] = 1.f / lsum[r];
  }
  // No __syncthreads: each wave only ever touches its own 16 rows of stash/invl.

  // ---- phase 2: coalesced dense attn row writes (512 MB stream; nt stores) ----
  const size_t arow = ((size_t)(b*16 + h))*2048;
  for (int it=0; it<128; ++it){
    int r     = rb + (it>>3);
    int inner = ((it&7)<<6) + lane;     // 512 float4-groups per row
    int j0    = inner*4;
    float inv  = invl[r];
    float sval = b2f(stash[r*SW2 + (inner>>1)]);      // strided slot (iff inner even)
    int off    = j0 - jl0;                            // local-window offset (mult of 4)
    int offc   = imin(imax(off,0),92);
    uint2 lvu  = *(const uint2*)&stash[r*SW2 + 256 + offc];  // 4 local bf16
    bool lok = (off>=0) && (off<96);
    float lx = lok ? b2f((ushort_t)(lvu.x & 0xffffu)) : 0.f;
    float ly = lok ? b2f((ushort_t)(lvu.x >> 16))     : 0.f;
    float lz = lok ? b2f((ushort_t)(lvu.y & 0xffffu)) : 0.f;
    float lw = lok ? b2f((ushort_t)(lvu.y >> 16))     : 0.f;
    f32x4 o;
    o[0] = ((inner&1)==0) ? inv*sval : inv*lx;        // j%8==0 -> strided value
    o[1] = inv*ly; o[2] = inv*lz; o[3] = inv*lw;
    __builtin_nontemporal_store(o, (f32x4*)&attn_out[(arow + i0 + r)*2048 + j0]);
  }

  // ---- phase 3: PV via MFMA ----
  // ctx[r,d] = sum_s P[r,s] * V[j(s),d].  A-frag = P rows (k-contiguous in
  // stash, 1 ds_read_b128/chunk vs 1408 broadcast b128 before).  B-frag = V
  // gathered with the SAME 352 scalar loads/wave the VALU version paid.
  f32x4 pacc[4];
  #pragma unroll
  for (int nt=0;nt<4;nt++) pacc[nt]=fz4();
  const ushort_t* prow = &stash[(rb + ml)*SW2];
  for (int ck=0; ck<11; ++ck){
    int s0 = ck*32;
    bf16x8 pa = __builtin_bit_cast(bf16x8, *(const uint4*)(prow + s0 + quad*8));
    ushort_t vr[4][8];
    #pragma unroll
    for (int e=0;e<8;e++){
      int s = s0 + quad*8 + e;
      int j = (s<256) ? 8*s : (jl0 + s - 256);
      int jc = imin(imax(j,0),2047);
      const ushort_t* vp = Vb + bh + (size_t)jc*1024 + ml;
      #pragma unroll
      for (int nt=0;nt<4;nt++) vr[nt][e] = vp[nt*16];
    }
    #pragma unroll
    for (int nt=0;nt<4;nt++){
      uint4 pk;
      pk.x = (uint)vr[nt][0] | ((uint)vr[nt][1]<<16);
      pk.y = (uint)vr[nt][2] | ((uint)vr[nt][3]<<16);
      pk.z = (uint)vr[nt][4] | ((uint)vr[nt][5]<<16);
      pk.w = (uint)vr[nt][6] | ((uint)vr[nt][7]<<16);
      bf16x8 bfr = __builtin_bit_cast(bf16x8, pk);
      pacc[nt] = __builtin_amdgcn_mfma_f32_16x16x32_bf16(pa, bfr, pacc[nt], 0,0,0);
    }
  }
  // D layout: row = quad*4+reg (within wave's 16-row tile), col = nt*16+ml
  #pragma unroll
  for (int nt=0;nt<4;nt++){
    #pragma unroll
    for (int rr=0;rr<4;rr++){
      int r = rb + quad*4 + rr;
      float val = pacc[nt][rr] * invl[r];
      Ctxb[bh + (size_t)(i0 + r)*1024 + nt*16 + ml] = f2b(val);
    }
  }
}

extern "C" void kernel_launch(void* const* d_in, const int* in_sizes, int n_in,
                              void* d_out, int out_size, void* d_ws, size_t ws_size,
                              hipStream_t stream) {
  (void)in_sizes; (void)n_in; (void)out_size; (void)ws_size;
  const float* query = (const float*)d_in[0];
  const float* key_  = (const float*)d_in[1];
  const float* value = (const float*)d_in[2];
  const float* Wq = (const float*)d_in[3];
  const float* bq = (const float*)d_in[4];
  const float* Wk = (const float*)d_in[5];
  const float* bk = (const float*)d_in[6];
  const float* Wv = (const float*)d_in[7];
  const float* bv = (const float*)d_in[8];
  const float* Wo = (const float*)d_in[9];
  const float* bo = (const float*)d_in[10];

  // Workspace: exactly 32 MB (Qb/Kb/Vb/Ctxb, bf16 4096x1024 each).
  char* ws = (char*)d_ws;
  ushort_t* Qb   = (ushort_t*)(ws);
  ushort_t* Kb   = (ushort_t*)(ws + (size_t)( 8<<20));
  ushort_t* Vb   = (ushort_t*)(ws + (size_t)(16<<20));
  ushort_t* Ctxb = (ushort_t*)(ws + (size_t)(24<<20));

  float* out = (float*)d_out;
  float* attn_out = out + (size_t)4096*1024;

  // Scratch: the 512 MB attn_out region is dead until attn_k writes it.
  // Converted bf16 activations (3x8 MB) + weights (3x2 MB) live there.
  ushort_t* scr = (ushort_t*)attn_out;
  ushort_t* Aq  = scr;
  ushort_t* Ak  = scr + (size_t)1*4096*1024;
  ushort_t* Av  = scr + (size_t)2*4096*1024;
  ushort_t* Wqb = scr + (size_t)3*4096*1024;
  ushort_t* Wkb = Wqb + (size_t)1024*1024;
  ushort_t* Wvb = Wkb + (size_t)1024*1024;
  // Wo converts into Qb's slot AFTER attn_k (Q dead by then).
  ushort_t* Wob = Qb;

  const int NA = 4096*1024/8;   // 524288 vec8 per activation matrix
  const int NW = 1024*1024/8;   // 131072 vec8 per weight matrix

  CJob ja{query, Aq, NA}, jb{key_, Ak, NA}, jc{value, Av, NA};
  CJob jd{Wq, Wqb, NW}, je{Wk, Wkb, NW}, jf{Wv, Wvb, NW};
  convert_k<<<dim3(1024,6), 256, 0, stream>>>(ja, jb, jc, jd, je, jf);

  GArg ga{Aq, Wqb, bq, Qb};
  GArg gb{Ak, Wkb, bk, Kb};
  GArg gc{Av, Wvb, bv, Vb};
  gemm_nt<true><<<dim3(8,32,3), 256, 0, stream>>>(ga, gb, gc);

  attn_k<<<dim3(64,16,2), 128, 0, stream>>>(Qb, Kb, Vb, Ctxb, attn_out);

  CJob jo{Wo, Wob, NW};
  convert_k<<<dim3(512,1), 256, 0, stream>>>(jo, jo, jo, jo, jo, jo);

  GArg go{Ctxb, Wob, bo, out};
  gemm_nt<false><<<dim3(8,32,1), 256, 0, stream>>>(go, go, go);
}

// Round 4
// 703.475 us; speedup vs baseline: 1.0508x; 1.0508x over previous
//
#include <hip/hip_runtime.h>

typedef unsigned int uint;
typedef unsigned short ushort_t;
typedef __bf16 bf16x8 __attribute__((ext_vector_type(8)));
typedef float f32x4 __attribute__((ext_vector_type(4)));

__device__ __forceinline__ int imin(int a, int b){ return a<b?a:b; }
__device__ __forceinline__ int imax(int a, int b){ return a>b?a:b; }

__device__ __forceinline__ ushort_t f2b(float f){
  uint u = __builtin_bit_cast(uint, f);
  u += 0x7FFFu + ((u>>16)&1u);          // round-to-nearest-even
  return (ushort_t)(u>>16);
}
__device__ __forceinline__ float b2f(ushort_t s){
  uint u = ((uint)s)<<16;
  return __builtin_bit_cast(float, u);
}
__device__ __forceinline__ f32x4 fz4(){ f32x4 z; z[0]=0.f; z[1]=0.f; z[2]=0.f; z[3]=0.f; return z; }

// async global->LDS, 16 B per lane. LDS dest = wave-uniform base + lane*16.
__device__ __forceinline__ void gload16(const void* g, void* lds){
  __builtin_amdgcn_global_load_lds(
      (const __attribute__((address_space(1))) void*)g,
      (__attribute__((address_space(3))) void*)lds,
      16, 0, 0);
}

// ---------------- fp32 -> bf16 pre-convert ----------------
struct CJob { const float* src; ushort_t* dst; int nvec; };  // nvec = elems/8

__global__ __launch_bounds__(256) void convert_k(CJob j0, CJob j1, CJob j2,
                                                 CJob j3, CJob j4, CJob j5)
{
  CJob jb;
  switch (blockIdx.y){
    case 0: jb=j0; break; case 1: jb=j1; break; case 2: jb=j2; break;
    case 3: jb=j3; break; case 4: jb=j4; break; default: jb=j5; break;
  }
  int stride = gridDim.x*256;
  for (int i = blockIdx.x*256 + threadIdx.x; i < jb.nvec; i += stride){
    const float4* s = (const float4*)(jb.src + (size_t)i*8);
    float4 v0 = s[0], v1 = s[1];
    uint4 pk;
    pk.x = (uint)f2b(v0.x) | ((uint)f2b(v0.y)<<16);
    pk.y = (uint)f2b(v0.z) | ((uint)f2b(v0.w)<<16);
    pk.z = (uint)f2b(v1.x) | ((uint)f2b(v1.y)<<16);
    pk.w = (uint)f2b(v1.z) | ((uint)f2b(v1.w)<<16);
    *(uint4*)(jb.dst + (size_t)i*8) = pk;
  }
}

// ---------------- GEMM: C[M,N] = A[M,K] @ W[N,K]^T + bias ----------------
// M=4096, N=1024, K=1024. 128x128 tile, BK=32, 256 threads (4 waves, 64x64).
// Staging via global_load_lds (16B/lane, linear LDS dest). Bank-conflict-free
// fragment reads via XOR swizzle: LDS[row][s] holds G[row][s ^ ((row>>1)&3)],
// realized by pre-swizzling the per-lane GLOBAL source col (rule 21) and
// XOR-ing the same term into the ds_read address. 16 lanes -> 8 distinct 16B
// slots covering all 32 banks -> 2-way (free).
struct GArg { const ushort_t* A; const ushort_t* W; const float* bias; void* O; };

template<bool OBF16>
__global__ __launch_bounds__(256) void gemm_nt(GArg g0, GArg g1, GArg g2)
{
  GArg g = (blockIdx.z==0) ? g0 : ((blockIdx.z==1) ? g1 : g2);
  __shared__ __align__(16) ushort_t As[128*32];
  __shared__ __align__(16) ushort_t Bs[128*32];
  const int tid  = threadIdx.x;
  const int lane = tid & 63;
  const int w    = tid >> 6;
  const int ml   = lane & 15, quad = lane >> 4;

  // XCD-aware block swizzle: 256 wgs per z-slice, 256%8==0 -> bijective.
  // XCD k gets 32 contiguous tiles (4 m-panels x all 8 n) -> A panels + full W
  // fit the 4 MiB per-XCD L2.
  int lid = blockIdx.x + 8*blockIdx.y;
  int t   = (lid & 7)*32 + (lid >> 3);
  const int m0 = (t >> 3)*128, n0 = (t & 7)*128;
  const int wm = (w>>1)*64, wn = (w&1)*64;

  // staging geometry: each gload16 call covers 16 rows (4 lanes/row).
  const int srow = lane >> 2;                       // 0..15
  const int scol = ((lane & 3) ^ ((lane >> 3) & 3))*8;  // pre-swizzled col
  const int rA0 = w*16, rA1 = 64 + w*16;
  const ushort_t* gA = g.A + (size_t)m0*1024;
  const ushort_t* gB = g.W + (size_t)n0*1024;
  // fragment-read swizzle term (same for all t4 since rows step by 16)
  const int sxor = (quad ^ ((ml >> 1) & 3))*8;

  f32x4 acc[4][4];
  #pragma unroll
  for (int i=0;i<4;i++)
    #pragma unroll
    for (int j=0;j<4;j++) acc[i][j]=fz4();

  for (int kt=0; kt<32; ++kt){
    int kof = kt*32 + scol;
    gload16(gA + (size_t)(rA0+srow)*1024 + kof, &As[rA0*32]);
    gload16(gA + (size_t)(rA1+srow)*1024 + kof, &As[rA1*32]);
    gload16(gB + (size_t)(rA0+srow)*1024 + kof, &Bs[rA0*32]);
    gload16(gB + (size_t)(rA1+srow)*1024 + kof, &Bs[rA1*32]);
    __syncthreads();    // compiler drains vmcnt before s_barrier

    bf16x8 af[4], bfr[4];
    #pragma unroll
    for (int t4=0;t4<4;t4++)
      af[t4]  = __builtin_bit_cast(bf16x8, *(const uint4*)&As[(wm + t4*16 + ml)*32 + sxor]);
    #pragma unroll
    for (int t4=0;t4<4;t4++)
      bfr[t4] = __builtin_bit_cast(bf16x8, *(const uint4*)&Bs[(wn + t4*16 + ml)*32 + sxor]);
    #pragma unroll
    for (int ti=0;ti<4;ti++)
      #pragma unroll
      for (int tj=0;tj<4;tj++)
        acc[ti][tj] = __builtin_amdgcn_mfma_f32_16x16x32_bf16(af[ti], bfr[tj], acc[ti][tj], 0,0,0);
    __syncthreads();
  }
  // ---- epilogue: C row=(lane>>4)*4+reg, col=lane&15 (m89-verified layout) ----
  #pragma unroll
  for (int tj=0;tj<4;tj++){
    int gcol = n0 + wn + tj*16 + ml;
    float bv = g.bias[gcol];
    #pragma unroll
    for (int ti=0;ti<4;ti++){
      int growb = m0 + wm + ti*16 + quad*4;
      #pragma unroll
      for (int r=0;r<4;r++){
        float val = acc[ti][tj][r] + bv;
        size_t off = (size_t)(growb + r)*1024 + gcol;
        if (OBF16) ((ushort_t*)g.O)[off] = f2b(val);
        else       ((float*)g.O)[off]    = val;
      }
    }
  }
}

// ---------------- sparse attention ----------------
// wg = (b, h, 32 query rows). 128 threads = 2 waves; wave w owns rows 16w..16w+15.
// Slots: 0..255 strided (j=8*slot), 256..351 local (j = i0-32 + slot-256).
#define SW2 360   // row stride in bf16 elems; 720 B -> decent bank spread
__global__ __launch_bounds__(128) void attn_k(
    const ushort_t* Qb, const ushort_t* Kb, const ushort_t* Vb,
    ushort_t* Ctxb, float* attn_out)
{
  __shared__ ushort_t stash[32*SW2];   // unnormalized exp(score), bf16
  __shared__ float invl[32];           // 1 / row-sum
  const int lane = threadIdx.x & 63;
  const int w    = threadIdx.x >> 6;
  const int ml   = lane & 15, quad = lane >> 4;
  // XCD swizzle: 2048 wgs, %8==0 bijective. Groups the 64 tiles sharing one
  // (b,h) K/V panel onto one XCD -> panel fetched once per XCD, not 8x.
  int lid = blockIdx.x + 64*(blockIdx.y + 16*blockIdx.z);
  int tt  = (lid & 7)*256 + (lid >> 3);
  const int tile = tt & 63, h = (tt >> 6) & 15, b = tt >> 10;
  const int i0  = tile*32;
  const int jl0 = i0 - 32;
  const int rb  = 16*w;
  const size_t bh = (size_t)b*2048*1024 + (size_t)h*64;

  // ---- phase 1: scores -> exp -> stash; row-sums ----
  bf16x8 aq0, aq1;
  {
    const ushort_t* qp = Qb + bh + (size_t)(i0 + rb + ml)*1024 + quad*8;
    aq0 = __builtin_bit_cast(bf16x8, *(const uint4*)qp);
    aq1 = __builtin_bit_cast(bf16x8, *(const uint4*)(qp + 32));
  }
  float lsum[4] = {0.f,0.f,0.f,0.f};
  for (int c=0;c<22;c++){
    int j  = (c<16) ? (128*c + 8*ml) : (jl0 + 16*(c-16) + ml);
    int jc = imin(imax(j,0),2047);
    const ushort_t* kp = Kb + bh + (size_t)jc*1024 + quad*8;
    bf16x8 kb0 = __builtin_bit_cast(bf16x8, *(const uint4*)kp);
    bf16x8 kb1 = __builtin_bit_cast(bf16x8, *(const uint4*)(kp + 32));
    f32x4 sc = fz4();
    sc = __builtin_amdgcn_mfma_f32_16x16x32_bf16(aq0, kb0, sc, 0,0,0);
    sc = __builtin_amdgcn_mfma_f32_16x16x32_bf16(aq1, kb1, sc, 0,0,0);
    int slot = 16*c + ml;
    #pragma unroll
    for (int r=0;r<4;r++){
      int rl = rb + quad*4 + r;
      int i  = i0 + rl;
      bool valid = (c<16) ? true :
        ((j>=0) && (j<2048) && ((j&7)!=0) && (j >= i-32) && (j < i+32));
      float e = valid ? __expf(sc[r]*0.125f) : 0.f;   // masked -> exact 0
      ushort_t eb = f2b(e);
      lsum[r] += b2f(eb);                 // sum the ROUNDED values: rows sum to 1
      stash[rl*SW2 + slot] = eb;
    }
  }
  #pragma unroll
  for (int off=1; off<16; off<<=1){
    #pragma unroll
    for (int r=0;r<4;r++) lsum[r] += __shfl_xor(lsum[r], off);
  }
  if (ml==0){
    #pragma unroll
    for (int r=0;r<4;r++) invl[rb + quad*4 + r] = 1.f / lsum[r];
  }
  // No __syncthreads: each wave only ever touches its own 16 rows of stash/invl.

  // ---- phase 2: coalesced dense attn row writes (512 MB stream; nt stores) ----
  const size_t arow = ((size_t)(b*16 + h))*2048;
  for (int it=0; it<128; ++it){
    int r     = rb + (it>>3);
    int inner = ((it&7)<<6) + lane;     // 512 float4-groups per row
    int j0    = inner*4;
    float inv  = invl[r];
    float sval = b2f(stash[r*SW2 + (inner>>1)]);      // strided slot (iff inner even)
    int off    = j0 - jl0;                            // local-window offset (mult of 4)
    int offc   = imin(imax(off,0),92);
    uint2 lvu  = *(const uint2*)&stash[r*SW2 + 256 + offc];  // 4 local bf16
    bool lok = (off>=0) && (off<96);
    float lx = lok ? b2f((ushort_t)(lvu.x & 0xffffu)) : 0.f;
    float ly = lok ? b2f((ushort_t)(lvu.x >> 16))     : 0.f;
    float lz = lok ? b2f((ushort_t)(lvu.y & 0xffffu)) : 0.f;
    float lw = lok ? b2f((ushort_t)(lvu.y >> 16))     : 0.f;
    f32x4 o;
    o[0] = ((inner&1)==0) ? inv*sval : inv*lx;        // j%8==0 -> strided value
    o[1] = inv*ly; o[2] = inv*lz; o[3] = inv*lw;
    __builtin_nontemporal_store(o, (f32x4*)&attn_out[(arow + i0 + r)*2048 + j0]);
  }

  // ---- phase 3: PV via MFMA ----
  f32x4 pacc[4];
  #pragma unroll
  for (int nt=0;nt<4;nt++) pacc[nt]=fz4();
  const ushort_t* prow = &stash[(rb + ml)*SW2];
  for (int ck=0; ck<11; ++ck){
    int s0 = ck*32;
    bf16x8 pa = __builtin_bit_cast(bf16x8, *(const uint4*)(prow + s0 + quad*8));
    ushort_t vr[4][8];
    #pragma unroll
    for (int e=0;e<8;e++){
      int s = s0 + quad*8 + e;
      int j = (s<256) ? 8*s : (jl0 + s - 256);
      int jc = imin(imax(j,0),2047);
      const ushort_t* vp = Vb + bh + (size_t)jc*1024 + ml;
      #pragma unroll
      for (int nt=0;nt<4;nt++) vr[nt][e] = vp[nt*16];
    }
    #pragma unroll
    for (int nt=0;nt<4;nt++){
      uint4 pk;
      pk.x = (uint)vr[nt][0] | ((uint)vr[nt][1]<<16);
      pk.y = (uint)vr[nt][2] | ((uint)vr[nt][3]<<16);
      pk.z = (uint)vr[nt][4] | ((uint)vr[nt][5]<<16);
      pk.w = (uint)vr[nt][6] | ((uint)vr[nt][7]<<16);
      bf16x8 bfr = __builtin_bit_cast(bf16x8, pk);
      pacc[nt] = __builtin_amdgcn_mfma_f32_16x16x32_bf16(pa, bfr, pacc[nt], 0,0,0);
    }
  }
  // D layout: row = quad*4+reg (within wave's 16-row tile), col = nt*16+ml
  #pragma unroll
  for (int nt=0;nt<4;nt++){
    #pragma unroll
    for (int rr=0;rr<4;rr++){
      int r = rb + quad*4 + rr;
      float val = pacc[nt][rr] * invl[r];
      Ctxb[bh + (size_t)(i0 + r)*1024 + nt*16 + ml] = f2b(val);
    }
  }
}

extern "C" void kernel_launch(void* const* d_in, const int* in_sizes, int n_in,
                              void* d_out, int out_size, void* d_ws, size_t ws_size,
                              hipStream_t stream) {
  (void)in_sizes; (void)n_in; (void)out_size; (void)ws_size;
  const float* query = (const float*)d_in[0];
  const float* key_  = (const float*)d_in[1];
  const float* value = (const float*)d_in[2];
  const float* Wq = (const float*)d_in[3];
  const float* bq = (const float*)d_in[4];
  const float* Wk = (const float*)d_in[5];
  const float* bk = (const float*)d_in[6];
  const float* Wv = (const float*)d_in[7];
  const float* bv = (const float*)d_in[8];
  const float* Wo = (const float*)d_in[9];
  const float* bo = (const float*)d_in[10];

  // Workspace: exactly 32 MB (Qb/Kb/Vb/Ctxb, bf16 4096x1024 each).
  char* ws = (char*)d_ws;
  ushort_t* Qb   = (ushort_t*)(ws);
  ushort_t* Kb   = (ushort_t*)(ws + (size_t)( 8<<20));
  ushort_t* Vb   = (ushort_t*)(ws + (size_t)(16<<20));
  ushort_t* Ctxb = (ushort_t*)(ws + (size_t)(24<<20));

  float* out = (float*)d_out;
  float* attn_out = out + (size_t)4096*1024;

  // Scratch: the 512 MB attn_out region is dead until attn_k overwrites it.
  ushort_t* scr = (ushort_t*)attn_out;
  ushort_t* Aq  = scr;
  ushort_t* Ak  = scr + (size_t)1*4096*1024;
  ushort_t* Av  = scr + (size_t)2*4096*1024;
  ushort_t* Wqb = scr + (size_t)3*4096*1024;
  ushort_t* Wkb = Wqb + (size_t)1024*1024;
  ushort_t* Wvb = Wkb + (size_t)1024*1024;
  // Wo converts into Qb's slot AFTER attn_k (Q dead by then).
  ushort_t* Wob = Qb;

  const int NA = 4096*1024/8;   // 524288 vec8 per activation matrix
  const int NW = 1024*1024/8;   // 131072 vec8 per weight matrix

  CJob ja{query, Aq, NA}, jb{key_, Ak, NA}, jc{value, Av, NA};
  CJob jd{Wq, Wqb, NW}, je{Wk, Wkb, NW}, jf{Wv, Wvb, NW};
  convert_k<<<dim3(1024,6), 256, 0, stream>>>(ja, jb, jc, jd, je, jf);

  GArg ga{Aq, Wqb, bq, Qb};
  GArg gb{Ak, Wkb, bk, Kb};
  GArg gc{Av, Wvb, bv, Vb};
  gemm_nt<true><<<dim3(8,32,3), 256, 0, stream>>>(ga, gb, gc);

  attn_k<<<dim3(64,16,2), 128, 0, stream>>>(Qb, Kb, Vb, Ctxb, attn_out);

  CJob jo{Wo, Wob, NW};
  convert_k<<<dim3(512,1), 256, 0, stream>>>(jo, jo, jo, jo, jo, jo);

  GArg go{Ctxb, Wob, bo, out};
  gemm_nt<false><<<dim3(8,32,1), 256, 0, stream>>>(go, go, go);
}